// Round 13
// baseline (211.998 us; speedup 1.0000x reference)
//
#include <hip/hip_runtime.h>
#include <hip/hip_fp8.h>

typedef unsigned char u8;
typedef unsigned short u16;
typedef int i32x4 __attribute__((ext_vector_type(4)));
typedef int i32x8 __attribute__((ext_vector_type(8)));
typedef float f32x4 __attribute__((ext_vector_type(4)));
typedef u16 u16x8 __attribute__((ext_vector_type(8)));
typedef u8 u8x16 __attribute__((ext_vector_type(16)));

#define HW_N 16384   // 128*128 pixels
#define NCH  2048
// A16 layout: [kc2 0..16][pixel 16384][128 B] fp8 e4m3, CANONICAL k (byte b = k kc2*128+b).
//   k 0..2047 = LN'd trans (z = k>>6); k 2048..2095 = dense features; 2096..2175 zero pad.
// W16 layout: [kc2 0..16][ch 2048][128 B], canonical, values pre-scaled x16, tail zero.
// Wd16 layout: [kc2 0..15][j 48][128 B], canonical, x16.
// LDS swizzle (k_gemm/k_dense): 16B chunk c of row r stored at pos c ^ (r&7)
//   (involution; write via pre-swizzled gload source, read pos q holds chunk q^(r&7)).

__device__ __forceinline__ u16 f2bf(float f) {
  union { float f; unsigned u; } v; v.f = f;
  unsigned r = v.u + 0x7FFFu + ((v.u >> 16) & 1u);
  return (u16)(r >> 16);
}
__device__ __forceinline__ float bf2f(u16 u) {
  union { unsigned u; float f; } v; v.u = ((unsigned)u) << 16; return v.f;
}
__device__ __forceinline__ u8 f2fp8(float f) {
  __hip_fp8_e4m3 t(f);
  return (u8)t.__x;
}
__device__ __forceinline__ float lrelu(float v) { return v >= 0.0f ? v : 0.2f * v; }

__device__ __forceinline__ void gload_lds16(const u8* g, u8* l) {
  __builtin_amdgcn_global_load_lds((const __attribute__((address_space(1))) void*)g,
                                   (__attribute__((address_space(3))) void*)l, 16, 0, 0);
}

// K=128 fp8 scaled MFMA, neutral E8M0 scales (0x7F = x1), fmt 0 = fp8 e4m3. (validated r11)
#define MFS(a, b, c) \
  __builtin_amdgcn_mfma_scale_f32_16x16x128_f8f6f4((a), (b), (c), 0, 0, 0, 0x7F7F7F7F, 0, 0x7F7F7F7F)

// read one K=128 fragment (32B/lane) from a swizzled 128B-row LDS region
#define RDFRAG(R, row, kg_, outv)                                              \
  {                                                                            \
    const int off_ = ((row) << 7) + ((((kg_) << 1) ^ ((row) & 7)) << 4);       \
    i32x4 lo_ = *(const i32x4*)((R) + off_);                                   \
    i32x4 hi_ = *(const i32x4*)((R) + (off_ ^ 16));                            \
    outv = __builtin_shufflevector(lo_, hi_, 0, 1, 2, 3, 4, 5, 6, 7);          \
  }

// ---------------- kernel 1: LN stats + pooled partial + coalesced fp8 A copy ----------------
__global__ __launch_bounds__(256) void k_stats(const float* __restrict__ trans,
                                               u8* __restrict__ A16,
                                               float* __restrict__ pooled_sum) {
  const int z = blockIdx.x;
  const int tid = threadIdx.x;
  const int ptile = blockIdx.y;
  const int p = ptile * 256 + tid;
  const float* src = trans + (size_t)z * 64 * HW_N + p;
  float x[64];
#pragma unroll
  for (int c = 0; c < 64; ++c) x[c] = src[(size_t)c * HW_N];
  float sum = 0.f, sq = 0.f;
#pragma unroll
  for (int c = 0; c < 64; ++c) { sum += x[c]; sq += x[c] * x[c]; }
  const float mu = sum * (1.0f / 64.0f);
  const float var = sq * (1.0f / 64.0f) - mu * mu;
  const float rstd = rsqrtf(var + 1e-5f);

  __shared__ __align__(16) u8 rawt[256 * 64];    // 16 KB fp8 (canonical, 4-slot bank swizzle)
  __shared__ __align__(16) u16 normt[256 * 64];  // 32 KB bf16 (pooling path)
  const int r3m = tid & 3, r7 = tid & 7;
#pragma unroll
  for (int c = 0; c < 4; ++c) {
    u8x16 y;
#pragma unroll
    for (int w = 0; w < 16; ++w) y[w] = f2fp8(x[c * 16 + w]);
    *(u8x16*)&rawt[tid * 64 + ((c ^ r3m) << 4)] = y;
  }
#pragma unroll
  for (int c8 = 0; c8 < 8; ++c8) {
    u16x8 wn;
#pragma unroll
    for (int e = 0; e < 8; ++e) wn[e] = f2bf((x[c8 * 8 + e] - mu) * rstd);
    *(u16x8*)&normt[tid * 64 + ((c8 ^ r7) << 3)] = wn;
  }
  __syncthreads();

  // writeout: 64B half-rows of A16 slab z>>1, byte offset (z&1)*64 (64B segments, aligned)
  u8* gbase = A16 + ((size_t)(z >> 1) * HW_N + (size_t)ptile * 256) * 128 + (z & 1) * 64;
#pragma unroll
  for (int it = 0; it < 4; ++it) {
    const int o = it * 256 + tid;
    const int row = o >> 2, c4 = o & 3;
    *(u8x16*)(gbase + (size_t)row * 128 + c4 * 16) =
        *(const u8x16*)&rawt[row * 64 + ((c4 ^ (row & 3)) << 4)];
  }

  // pooled[z][c] partial from norm tile
  const int c = tid & 63, q = tid >> 6;
  const int kc2 = c >> 3, e2 = c & 7;
  float s = 0.f;
#pragma unroll 8
  for (int i = 0; i < 64; ++i) {
    const int row = q * 64 + i;
    s += bf2f(normt[row * 64 + ((kc2 ^ (row & 7)) << 3) + e2]);
  }
  __shared__ float red2[4][64];
  red2[q][c] = s;
  __syncthreads();
  if (tid < 64) {
    atomicAdd(&pooled_sum[z * 64 + tid],
              red2[0][tid] + red2[1][tid] + red2[2][tid] + red2[3][tid]);
  }
}

// ---------------- kernel 2: pack fuse_w -> W16 AND dense weights -> Wd16 (one dispatch) ------
// grid (33, 33): yb<32 -> W16 tile (ktile 0..32, ntile); yb==32 -> Wd16 (kc=ktile<32).
__global__ __launch_bounds__(256) void k_wpack(const float* __restrict__ fw,
                                               const float* __restrict__ dw0,
                                               const float* __restrict__ dw1,
                                               const float* __restrict__ dw2,
                                               u8* __restrict__ W16,
                                               u8* __restrict__ Wd16) {
  __shared__ float tile[64][65];
  const int tid = threadIdx.x;
  const int ktile = blockIdx.x;
  const int yb = blockIdx.y;
  if (yb == 32) {
    const int kc = ktile;
    if (kc >= 32) return;
    for (int idx = tid; idx < 3072; idx += 256) {
      const int kk = idx / 48, j = idx % 48;
      const int k = kc * 64 + kk;
      float v = (j < 16) ? dw0[k * 16 + j]
              : (j < 32) ? dw1[k * 16 + (j - 16)]
                         : dw2[k * 16 + (j - 32)];
      tile[kk][j] = v;
    }
    __syncthreads();
    for (int idx = tid; idx < 3072; idx += 256) {
      const int j = idx / 64, kk = idx % 64;
      Wd16[((size_t)(kc >> 1) * 48 + j) * 128 + (kc & 1) * 64 + kk] = f2fp8(16.0f * tile[kk][j]);
    }
    return;
  }
  const int ntile = yb;
  {
    const int kk0 = tid >> 6, nn = tid & 63;
#pragma unroll
    for (int it = 0; it < 16; ++it) {
      int kk = it * 4 + kk0;
      int kg = ktile * 64 + kk;
      tile[kk][nn] = (kg < 2096) ? fw[(size_t)kg * NCH + ntile * 64 + nn] : 0.0f;
    }
  }
  __syncthreads();
  {
    const int kk = tid & 63, nn0 = tid >> 6;
#pragma unroll
    for (int it = 0; it < 16; ++it) {
      int n = it * 4 + nn0;
      W16[((size_t)(ktile >> 1) * NCH + ntile * 64 + n) * 128 + (ktile & 1) * 64 + kk] =
          f2fp8(16.0f * tile[kk][n]);
    }
  }
}

// ---------------- kernel 3: dense chain fused (K=128 MFS GEMM + f0/f1/f2 + pack slab 16) ----
// grid 128 x 256 thr. 128 pixels/block, 16 steps of K=128.
__global__ __launch_bounds__(256) void k_dense(const u8* __restrict__ A16,
    const u8* __restrict__ Wd16,
    const float* __restrict__ dw1, const float* __restrict__ dw2,
    const float* __restrict__ db0, const float* __restrict__ db1,
    const float* __restrict__ db2, u8* __restrict__ A16out) {
  __shared__ __align__(16) u8 lsA[128 * 128];  // 16 KB
  __shared__ __align__(16) u8 lsW[48 * 128];   // 6 KB
  __shared__ float trn[128][49];               // 24.5 KB
  __shared__ float w1t[16][16];
  __shared__ float w2t[32][16];
  __shared__ float biases[48];
  const int tid = threadIdx.x;
  const int lane = tid & 63;
  const int wave = __builtin_amdgcn_readfirstlane(tid >> 6);
  const int mb = blockIdx.x;
  const int r16 = lane & 15, kg = lane >> 4;
  const int srow8 = lane >> 3;
  const int schunk = (((lane & 7) ^ srow8) << 4);

  if (tid < 256) w1t[tid >> 4][tid & 15] = dw1[(2048 + (tid >> 4)) * 16 + (tid & 15)];
  for (int idx = tid; idx < 512; idx += 256)
    w2t[idx >> 4][idx & 15] = dw2[(2048 + (idx >> 4)) * 16 + (idx & 15)];
  if (tid < 48) biases[tid] = (tid < 16) ? db0[tid] : (tid < 32) ? db1[tid - 16] : db2[tid - 32];

  f32x4 acc[3][2] = {};
  for (int t = 0; t < 16; ++t) {
    const u8* Asl = A16 + ((size_t)t * HW_N + (size_t)mb * 128) * 128;
    const u8* Wsl = Wd16 + (size_t)t * 48 * 128;
#pragma unroll
    for (int i = 0; i < 4; ++i) {
      const int r0 = wave * 32 + i * 8;
      gload_lds16(Asl + (size_t)(r0 + srow8) * 128 + schunk, lsA + r0 * 128 + lane * 16);
    }
    if (wave < 3) {
#pragma unroll
      for (int i = 0; i < 2; ++i) {
        const int r0 = wave * 16 + i * 8;
        gload_lds16(Wsl + (size_t)(r0 + srow8) * 128 + schunk, lsW + r0 * 128 + lane * 16);
      }
    }
    asm volatile("s_waitcnt vmcnt(0)" ::: "memory");
    __syncthreads();

    i32x8 wf[3], af[2];
#pragma unroll
    for (int f = 0; f < 3; ++f) RDFRAG(lsW, f * 16 + r16, kg, wf[f]);
#pragma unroll
    for (int g = 0; g < 2; ++g) RDFRAG(lsA, wave * 32 + g * 16 + r16, kg, af[g]);
#pragma unroll
    for (int f = 0; f < 3; ++f)
#pragma unroll
      for (int g = 0; g < 2; ++g)
        acc[f][g] = MFS(wf[f], af[g], acc[f][g]);
    __syncthreads();
  }

  // acc -> LDS transpose: trn[pixel][j]
  const int rg = lane >> 4;
#pragma unroll
  for (int f = 0; f < 3; ++f)
#pragma unroll
    for (int r = 0; r < 4; ++r)
#pragma unroll
      for (int g = 0; g < 2; ++g)
        trn[wave * 32 + g * 16 + r16][f * 16 + rg * 4 + r] = acc[f][g][r] * 0.0625f;
  __syncthreads();

  if (tid < 128) {
    float gv[48];
#pragma unroll
    for (int j = 0; j < 48; ++j) gv[j] = trn[tid][j];
    float f0[16], f1[16], f2[16];
#pragma unroll
    for (int j = 0; j < 16; ++j) f0[j] = lrelu(gv[j] + biases[j]);
#pragma unroll
    for (int j = 0; j < 16; ++j) {
      float a = gv[16 + j] + biases[16 + j];
#pragma unroll
      for (int i = 0; i < 16; ++i) a += f0[i] * w1t[i][j];
      f1[j] = lrelu(a);
    }
#pragma unroll
    for (int j = 0; j < 16; ++j) {
      float a = gv[32 + j] + biases[32 + j];
#pragma unroll
      for (int i = 0; i < 16; ++i) a += f0[i] * w2t[i][j];
#pragma unroll
      for (int i = 0; i < 16; ++i) a += f1[i] * w2t[16 + i][j];
      f2[j] = lrelu(a);
    }
    u8* dst = A16out + ((size_t)16 * HW_N + mb * 128 + tid) * 128;
#pragma unroll
    for (int c = 0; c < 3; ++c) {   // 48 dense bytes; 48..127 stay memset-zero
      u8x16 y;
#pragma unroll
      for (int w = 0; w < 16; ++w) {
        const int k = c * 16 + w;
        const float v = (k < 16) ? f0[k] : (k < 32) ? f1[k - 16] : f2[k - 32];
        y[w] = f2fp8(v);
      }
      *(u8x16*)(dst + c * 16) = y;
    }
  }
}

// ---------------- kernel 4: tiny z-axis attention ----------------
__global__ __launch_bounds__(256) void k_attn(const float* __restrict__ pooled_sum,
    const float* __restrict__ ln_w, const float* __restrict__ ln_b,
    const float* __restrict__ wq, const float* __restrict__ bq,
    const float* __restrict__ wk, const float* __restrict__ bk,
    const float* __restrict__ wv, const float* __restrict__ bv,
    const float* __restrict__ wo, const float* __restrict__ bo,
    const float* __restrict__ relz, const float* __restrict__ attn_gamma,
    float* __restrict__ o_scaled) {
  __shared__ float pooled[2048];
  __shared__ float q[512], k[512], v[512], att[4096], tz[512];
  const int tid = threadIdx.x;
  for (int i = tid; i < 2048; i += 256) {
    int c = i & 63;
    pooled[i] = ln_w[c] * pooled_sum[i] * (1.0f / 16384.0f) + ln_b[c];
  }
  __syncthreads();
  for (int i = tid; i < 512; i += 256) {
    int z = i >> 4, e = i & 15;
    float aq = bq[e], ak = bk[e], av = bv[e];
    for (int c = 0; c < 64; ++c) {
      float p = pooled[z * 64 + c];
      aq += p * wq[c * 16 + e]; ak += p * wk[c * 16 + e]; av += p * wv[c * 16 + e];
    }
    q[i] = aq; k[i] = ak; v[i] = av;
  }
  __syncthreads();
  if (tid < 128) {
    int h = tid >> 5, zi = tid & 31;
    float s[32]; float mx = -1e30f;
#pragma unroll
    for (int j = 0; j < 32; ++j) {
      float d = 0.f;
#pragma unroll
      for (int e = 0; e < 4; ++e) d += q[zi * 16 + h * 4 + e] * k[j * 16 + h * 4 + e];
      d = d * 0.5f + relz[h * 65 + (j - zi + 32)];
      s[j] = d; mx = fmaxf(mx, d);
    }
    float ssum = 0.f;
#pragma unroll
    for (int j = 0; j < 32; ++j) { s[j] = __expf(s[j] - mx); ssum += s[j]; }
    float inv = 1.0f / ssum;
#pragma unroll
    for (int j = 0; j < 32; ++j) att[(h * 32 + zi) * 32 + j] = s[j] * inv;
  }
  __syncthreads();
  for (int i = tid; i < 512; i += 256) {
    int z = i >> 4, hd = i & 15, h = hd >> 2;
    float a = 0.f;
    for (int j = 0; j < 32; ++j) a += att[(h * 32 + z) * 32 + j] * v[j * 16 + hd];
    tz[i] = a;
  }
  __syncthreads();
  const float gamma = attn_gamma[0];
  for (int i = tid; i < 2048; i += 256) {
    int z = i >> 6, c = i & 63;
    float a = bo[c];
    for (int hd = 0; hd < 16; ++hd) a += tz[z * 16 + hd] * wo[hd * 64 + c];
    o_scaled[i] = gamma * a;
  }
}

// ---------------- kernel 5: main GEMM, fp8 K=128 MFS, 256x256, 8-wave, single-buf 2-phase ----
// 17 steps BK=128. LDS 64 KB (A 32K + W 32K, one buffer) -> 2 blocks/CU; sibling-block
// overlap hides the per-step stage drain. Per step: 8 gloads + 24 b128 + 32 MFS + 2 barriers.
__global__ __launch_bounds__(512, 2) void k_gemm(
    const u8* __restrict__ A16, const u8* __restrict__ W16,
    const float* __restrict__ trans, const float* __restrict__ o_scaled,
    const float* __restrict__ fuse_b, const float* __restrict__ rdc_scale,
    float* __restrict__ out) {
  __shared__ __align__(16) u8 ls[65536];  // A: [0,32768) 256 rows; W: [32768,65536) 256 rows
  const int tid = threadIdx.x;
  const int lane = tid & 63;
  const int wave = __builtin_amdgcn_readfirstlane(tid >> 6);
  const int bid = blockIdx.x;
  const int nb = bid & 7;        // XCD owns one 256-ch W panel (557 KB, L2-resident)
  const int mb = bid >> 3;
  const int mbase = mb * 256, nbase = nb * 256;
  const int wm = wave & 1;       // pixel half (128)
  const int wn = wave >> 1;      // channel quarter (64)
  const int r16 = lane & 15, kg = lane >> 4;
  const int srow8 = lane >> 3;
  const int schunk = (((lane & 7) ^ srow8) << 4);
  u8* const lsA = ls;
  u8* const lsW = ls + 32768;

  f32x4 acc[4][8] = {};   // [f: 4 ch-frags][g: 8 pix-frags]

  for (int t = 0; t < 17; ++t) {
    const u8* Asl = A16 + ((size_t)t * HW_N + mbase) * 128;
    const u8* Wsl = W16 + ((size_t)t * NCH + nbase) * 128;
    // ---- stage phase: each wave stages 32 A rows + 32 W rows (4+4 gloads) ----
#pragma unroll
    for (int i = 0; i < 4; ++i) {
      const int r0 = wave * 32 + i * 8;
      gload_lds16(Asl + (size_t)(r0 + srow8) * 128 + schunk, lsA + r0 * 128 + lane * 16);
    }
#pragma unroll
    for (int i = 0; i < 4; ++i) {
      const int r0 = wave * 32 + i * 8;
      gload_lds16(Wsl + (size_t)(r0 + srow8) * 128 + schunk, lsW + r0 * 128 + lane * 16);
    }
    asm volatile("s_waitcnt vmcnt(0)" ::: "memory");
    __builtin_amdgcn_s_barrier();

    // ---- compute phase ----
    i32x8 wf[4];
#pragma unroll
    for (int f = 0; f < 4; ++f) RDFRAG(lsW, wn * 64 + f * 16 + r16, kg, wf[f]);
    __builtin_amdgcn_s_setprio(1);
#pragma unroll
    for (int g = 0; g < 8; ++g) {
      i32x8 af;
      RDFRAG(lsA, wm * 128 + g * 16 + r16, kg, af);
#pragma unroll
      for (int f = 0; f < 4; ++f)
        acc[f][g] = MFS(wf[f], af, acc[f][g]);
    }
    __builtin_amdgcn_s_setprio(0);
    __builtin_amdgcn_s_barrier();
  }

  // epilogue: out = trans + rdc*lrelu(acc/16 + fuse_b) + o_scaled   (/16 undoes W scale)
  const float rdc = rdc_scale[0];
  const int rg = lane >> 4;
#pragma unroll
  for (int f = 0; f < 4; ++f) {
#pragma unroll
    for (int r = 0; r < 4; ++r) {
      const int row = nbase + wn * 64 + f * 16 + rg * 4 + r;  // channel
      const float ob = o_scaled[row], fb = fuse_b[row];
#pragma unroll
      for (int g = 0; g < 8; ++g) {
        const int col = mbase + wm * 128 + g * 16 + r16;       // pixel
        float v = lrelu(acc[f][g][r] * 0.0625f + fb);
        const size_t idx = (size_t)row * HW_N + col;
        out[idx] = trans[idx] + rdc * v + ob;
      }
    }
  }
}

extern "C" void kernel_launch(void* const* d_in, const int* in_sizes, int n_in,
                              void* d_out, int out_size, void* d_ws, size_t ws_size,
                              hipStream_t stream) {
  (void)in_sizes; (void)n_in; (void)out_size; (void)ws_size;
  const float* trans = (const float*)d_in[0];
  const float* ln_w  = (const float*)d_in[1];
  const float* ln_b  = (const float*)d_in[2];
  const float* wq = (const float*)d_in[3];  const float* bq = (const float*)d_in[4];
  const float* wk = (const float*)d_in[5];  const float* bk = (const float*)d_in[6];
  const float* wv = (const float*)d_in[7];  const float* bv = (const float*)d_in[8];
  const float* wo = (const float*)d_in[9];  const float* bo = (const float*)d_in[10];
  const float* relz  = (const float*)d_in[11];
  const float* gamma = (const float*)d_in[12];
  const float* dw0 = (const float*)d_in[13]; const float* db0 = (const float*)d_in[14];
  const float* dw1 = (const float*)d_in[15]; const float* db1 = (const float*)d_in[16];
  const float* dw2 = (const float*)d_in[17]; const float* db2 = (const float*)d_in[18];
  const float* fuse_w = (const float*)d_in[19];
  const float* fuse_b = (const float*)d_in[20];
  const float* rdc    = (const float*)d_in[21];
  float* out = (float*)d_out;

  char* ws = (char*)d_ws;
  u8*    A16        = (u8*)ws;                       // 17*16384*128 = 35,651,584 B
  u8*    W16        = (u8*)(ws + 35651584);          // 17*2048*128  =  4,456,448 B
  u8*    Wd16       = (u8*)(ws + 40108032);          // 16*48*128    =     98,304 B
  float* pooled_sum = (float*)(ws + 40206336);       // 8 KB
  float* o_scaled   = (float*)(ws + 40214528);       // 8 KB

  hipMemsetAsync(pooled_sum, 0, 2048 * sizeof(float), stream);
  hipMemsetAsync(A16 + (size_t)16 * HW_N * 128, 0, (size_t)HW_N * 128, stream);  // K-pad slab
  hipMemsetAsync(W16 + (size_t)16 * NCH * 128, 0, (size_t)NCH * 128, stream);    // K-pad slab
  k_stats<<<dim3(32, 64), 256, 0, stream>>>(trans, A16, pooled_sum);
  k_wpack<<<dim3(33, 33), 256, 0, stream>>>(fuse_w, dw0, dw1, dw2, W16, Wd16);
  k_dense<<<dim3(128), 256, 0, stream>>>(A16, Wd16, dw1, dw2, db0, db1, db2, A16);
  k_attn<<<dim3(1), 256, 0, stream>>>(pooled_sum, ln_w, ln_b, wq, bq, wk, bk, wv, bv,
                                      wo, bo, relz, gamma, o_scaled);
  k_gemm<<<dim3(512), 512, 0, stream>>>(A16, W16, trans, o_scaled, fuse_b, rdc, out);
}